// Round 1
// baseline (917.240 us; speedup 1.0000x reference)
//
#include <hip/hip_runtime.h>
#include <math.h>

#define BB 8
#define NN 4096
#define DD 64
#define KNN 16

// broadcast lane l of x to all lanes via v_readlane (SGPR result)
__device__ __forceinline__ float bcastf(float x, int l) {
    return __int_as_float(__builtin_amdgcn_readlane(__float_as_int(x), l));
}

// Maintain descending-sorted top-16 (d[0] = current max = 16th smallest).
// Strict < keeps earliest (smallest index) on ties, matching lax.top_k.
__device__ __forceinline__ void insert16(float (&d)[16], int (&id)[16], float x, int m) {
    if (x < d[0]) {
        d[0] = x; id[0] = m;
#pragma unroll
        for (int j = 0; j < 15; ++j) {
            bool sw = d[j] < d[j + 1];
            float a0 = d[j], a1 = d[j + 1];
            int b0 = id[j], b1 = id[j + 1];
            d[j] = sw ? a1 : a0; d[j + 1] = sw ? a0 : a1;
            id[j] = sw ? b1 : b0; id[j + 1] = sw ? b0 : b1;
        }
    }
}

// ---------------- kNN: per-chunk partial top-16 ----------------
__global__ __launch_bounds__(64) void knn_chunk_kernel(const float* __restrict__ xyz,
                                                       float2* __restrict__ partial,
                                                       int nchunk) {
    const int chunkN = NN / nchunk;
    int bid = blockIdx.x;
    int c = bid % nchunk;
    int qc = (bid / nchunk) % (NN / 64);
    int b = bid / (nchunk * (NN / 64));
    int tid = threadIdx.x;
    int n = qc * 64 + tid;

    const float* xb = xyz + (size_t)b * NN * 3;
    float qx = xb[n * 3 + 0], qy = xb[n * 3 + 1], qz = xb[n * 3 + 2];
    // sq = (x*x + y*y) + z*z, no fma contraction (mirror XLA)
    float sqq = __fadd_rn(__fadd_rn(__fmul_rn(qx, qx), __fmul_rn(qy, qy)), __fmul_rn(qz, qz));

    float d[16]; int id[16];
#pragma unroll
    for (int j = 0; j < 16; ++j) { d[j] = 3.0e38f; id[j] = 0; }

    __shared__ float4 cs[512];
    for (int t0 = c * chunkN; t0 < (c + 1) * chunkN; t0 += 512) {
        __syncthreads();
        for (int i = tid; i < 512; i += 64) {
            int m = t0 + i;
            float x = xb[m * 3 + 0], y = xb[m * 3 + 1], z = xb[m * 3 + 2];
            float sq = __fadd_rn(__fadd_rn(__fmul_rn(x, x), __fmul_rn(y, y)), __fmul_rn(z, z));
            cs[i] = make_float4(x, y, z, sq);
        }
        __syncthreads();
        for (int j = 0; j < 512; ++j) {
            float4 cd = cs[j];  // same address across wave -> broadcast
            float dot = __fadd_rn(__fadd_rn(__fmul_rn(qx, cd.x), __fmul_rn(qy, cd.y)),
                                  __fmul_rn(qz, cd.z));
            float dist = __fadd_rn(__fadd_rn(sqq, cd.w), -__fmul_rn(2.0f, dot));
            insert16(d, id, dist, t0 + j);
        }
    }
    size_t base = ((size_t)(b * NN + n) * nchunk + c) * 16;
#pragma unroll
    for (int r = 0; r < 16; ++r)  // write ascending for ordered merge stream
        partial[base + r] = make_float2(d[15 - r], __int_as_float(id[15 - r]));
}

// ---------------- kNN: merge partials ----------------
__global__ __launch_bounds__(256) void knn_merge_kernel(const float2* __restrict__ partial,
                                                        int* __restrict__ knn, int nchunk) {
    int gq = blockIdx.x * 256 + threadIdx.x;
    if (gq >= BB * NN) return;
    float d[16]; int id[16];
#pragma unroll
    for (int j = 0; j < 16; ++j) { d[j] = 3.0e38f; id[j] = 0; }
    const float2* p = partial + (size_t)gq * nchunk * 16;
    for (int c = 0; c < nchunk; ++c) {
#pragma unroll
        for (int r = 0; r < 16; ++r) {
            float2 v = p[c * 16 + r];
            insert16(d, id, v.x, __float_as_int(v.y));
        }
    }
    int* o = knn + (size_t)gq * 16;
#pragma unroll
    for (int r = 0; r < 16; ++r) o[r] = id[r];
}

// ---------------- q/k/v projections ----------------
__global__ __launch_bounds__(256) void qkv_kernel(const float* __restrict__ feats,
                                                  const float* __restrict__ Wq,
                                                  const float* __restrict__ Wk,
                                                  const float* __restrict__ Wv,
                                                  float* __restrict__ Q,
                                                  float* __restrict__ Kf,
                                                  float* __restrict__ Vf) {
    __shared__ float Aq[4096], Ak[4096], Av[4096];
    int tid = threadIdx.x;
    for (int i = tid; i < 4096; i += 256) { Aq[i] = Wq[i]; Ak[i] = Wk[i]; Av[i] = Wv[i]; }
    __syncthreads();
    int lane = tid & 63, wid = tid >> 6;
    int gw = blockIdx.x * 4 + wid, nw = gridDim.x * 4;
    for (int r = gw; r < BB * NN; r += nw) {
        float f = feats[(size_t)r * 64 + lane];
        float aq = 0.f, ak = 0.f, av = 0.f;
#pragma unroll 8
        for (int h = 0; h < 64; ++h) {
            float s = bcastf(f, h);
            aq = fmaf(s, Aq[h * 64 + lane], aq);
            ak = fmaf(s, Ak[h * 64 + lane], ak);
            av = fmaf(s, Av[h * 64 + lane], av);
        }
        Q[(size_t)r * 64 + lane] = aq;
        Kf[(size_t)r * 64 + lane] = ak;
        Vf[(size_t)r * 64 + lane] = av;
    }
}

// ---------------- fused attention (per point, wave = point, lane = channel) ----------------
__global__ __launch_bounds__(256) void attn_kernel(
    const float* __restrict__ xyz, const float* __restrict__ feats,
    const float* __restrict__ Q, const float* __restrict__ Kf, const float* __restrict__ Vf,
    const int* __restrict__ knn,
    const float* __restrict__ d1w, const float* __restrict__ d1b,
    const float* __restrict__ d2w, const float* __restrict__ d2b,
    const float* __restrict__ g1w, const float* __restrict__ g1b,
    const float* __restrict__ g2w, const float* __restrict__ g2b,
    float* __restrict__ out, float* __restrict__ gsum, float* __restrict__ gsq) {
    __shared__ float W2s[4096], G1s[4096], G2s[4096];
    __shared__ float W1s[192], b1s[64], b2s[64], gb1s[64], gb2s[64];
    __shared__ float bns[64], bnq[64];
    int tid = threadIdx.x;
    for (int i = tid; i < 4096; i += 256) { W2s[i] = d2w[i]; G1s[i] = g1w[i]; G2s[i] = g2w[i]; }
    if (tid < 192) W1s[tid] = d1w[tid];
    if (tid < 64) {
        b1s[tid] = d1b[tid]; b2s[tid] = d2b[tid];
        gb1s[tid] = g1b[tid]; gb2s[tid] = g2b[tid];
        bns[tid] = 0.f; bnq[tid] = 0.f;
    }
    __syncthreads();

    int lane = tid & 63, wid = tid >> 6;
    int gw = blockIdx.x * 4 + wid, nw = gridDim.x * 4;
    float lsum = 0.f, lsq = 0.f;

    for (int p = gw; p < BB * NN; p += nw) {
        int b = p >> 12;
        float q = Q[(size_t)p * 64 + lane];
        float fres = feats[(size_t)p * 64 + lane];
        float xn0 = xyz[(size_t)p * 3 + 0];
        float xn1 = xyz[(size_t)p * 3 + 1];
        float xn2 = xyz[(size_t)p * 3 + 2];
        int iv = knn[(size_t)p * 16 + (lane & 15)];

        float kf[16], vf[16], hid[16];
#pragma unroll
        for (int k = 0; k < 16; ++k) {
            int idx = __builtin_amdgcn_readlane(iv, k);
            size_t row = (size_t)((b << 12) + idx);
            kf[k] = Kf[row * 64 + lane];
            vf[k] = Vf[row * 64 + lane];
            float dx = xn0 - xyz[row * 3 + 0];
            float dy = xn1 - xyz[row * 3 + 1];
            float dz = xn2 - xyz[row * 3 + 2];
            float hh = b1s[lane];
            hh = fmaf(dx, W1s[lane], hh);
            hh = fmaf(dy, W1s[64 + lane], hh);
            hh = fmaf(dz, W1s[128 + lane], hh);
            hid[k] = fmaxf(hh, 0.f);
        }

        float pe[16];
#pragma unroll
        for (int k = 0; k < 16; ++k) pe[k] = b2s[lane];
        for (int h = 0; h < 64; ++h) {
            float w = W2s[(h << 6) + lane];
#pragma unroll
            for (int k = 0; k < 16; ++k) pe[k] = fmaf(bcastf(hid[k], h), w, pe[k]);
        }

        float a[16];
#pragma unroll
        for (int k = 0; k < 16; ++k) a[k] = q - kf[k] + pe[k];

        float h2[16];
#pragma unroll
        for (int k = 0; k < 16; ++k) h2[k] = gb1s[lane];
        for (int h = 0; h < 64; ++h) {
            float w = G1s[(h << 6) + lane];
#pragma unroll
            for (int k = 0; k < 16; ++k) h2[k] = fmaf(bcastf(a[k], h), w, h2[k]);
        }
#pragma unroll
        for (int k = 0; k < 16; ++k) h2[k] = fmaxf(h2[k], 0.f);

        float lg[16];
#pragma unroll
        for (int k = 0; k < 16; ++k) lg[k] = gb2s[lane];
        for (int h = 0; h < 64; ++h) {
            float w = G2s[(h << 6) + lane];
#pragma unroll
            for (int k = 0; k < 16; ++k) lg[k] = fmaf(bcastf(h2[k], h), w, lg[k]);
        }

        float mx = lg[0];
#pragma unroll
        for (int k = 1; k < 16; ++k) mx = fmaxf(mx, lg[k]);
        float s = 0.f, acc = 0.f;
#pragma unroll
        for (int k = 0; k < 16; ++k) {
            float w = __expf(lg[k] - mx);
            s += w;
            acc = fmaf(w, vf[k] + pe[k], acc);
        }
        float res = acc / s + fres;
        out[(size_t)p * 64 + lane] = res;
        lsum += res;
        lsq = fmaf(res, res, lsq);
    }
    atomicAdd(&bns[lane], lsum);
    atomicAdd(&bnq[lane], lsq);
    __syncthreads();
    if (tid < 64) {
        atomicAdd(&gsum[tid], bns[tid]);
        atomicAdd(&gsq[tid], bnq[tid]);
    }
}

// ---------------- zero stats ----------------
__global__ void zero_stats_kernel(float* s) {
    if (threadIdx.x < 128) s[threadIdx.x] = 0.f;
}

// ---------------- BatchNorm finalize (in place on d_out) ----------------
__global__ __launch_bounds__(256) void bn_final_kernel(float* __restrict__ out,
                                                       const float* __restrict__ gsum,
                                                       const float* __restrict__ gsq,
                                                       const float* __restrict__ bnw,
                                                       const float* __restrict__ bnb) {
    __shared__ float sc[64], sh[64];
    int tid = threadIdx.x;
    if (tid < 64) {
        const float invN = 1.0f / (float)(BB * NN);
        float mean = gsum[tid] * invN;
        float var = gsq[tid] * invN - mean * mean;
        float inv = rsqrtf(var + 1e-5f);
        float scale = inv * bnw[tid];
        sc[tid] = scale;
        sh[tid] = bnb[tid] - mean * scale;
    }
    __syncthreads();
    size_t total = (size_t)BB * NN * 64;
    for (size_t i = (size_t)blockIdx.x * 256 + tid; i < total; i += (size_t)gridDim.x * 256) {
        int c = (int)(i & 63);
        out[i] = fmaf(out[i], sc[c], sh[c]);
    }
}

extern "C" void kernel_launch(void* const* d_in, const int* in_sizes, int n_in,
                              void* d_out, int out_size, void* d_ws, size_t ws_size,
                              hipStream_t stream) {
    const float* xyz = (const float*)d_in[0];
    const float* feats = (const float*)d_in[1];
    const float* Wq = (const float*)d_in[2];
    const float* Wk = (const float*)d_in[3];
    const float* Wv = (const float*)d_in[4];
    const float* d1w = (const float*)d_in[5];
    const float* d1b = (const float*)d_in[6];
    const float* d2w = (const float*)d_in[7];
    const float* d2b = (const float*)d_in[8];
    const float* g1w = (const float*)d_in[9];
    const float* g1b = (const float*)d_in[10];
    const float* g2w = (const float*)d_in[11];
    const float* g2b = (const float*)d_in[12];
    const float* bnw = (const float*)d_in[13];
    const float* bnb = (const float*)d_in[14];
    float* out = (float*)d_out;

    // choose number of kNN candidate chunks that fits in workspace
    int nchunk = 8;
    auto need = [](int nc) {
        return (size_t)BB * NN * nc * 16 * 8    // partials (float2)
             + (size_t)BB * NN * 16 * 4         // knn idx
             + 3 * (size_t)BB * NN * 64 * 4     // Q, Kf, Vf
             + 1024;                            // stats + pad
    };
    while (nchunk > 1 && need(nchunk) > ws_size) nchunk >>= 1;

    char* ws = (char*)d_ws;
    size_t off = 0;
    float2* partial = (float2*)(ws + off); off += (size_t)BB * NN * nchunk * 16 * 8;
    int* knn = (int*)(ws + off); off += (size_t)BB * NN * 16 * 4;
    float* Q = (float*)(ws + off); off += (size_t)BB * NN * 64 * 4;
    float* Kf = (float*)(ws + off); off += (size_t)BB * NN * 64 * 4;
    float* Vf = (float*)(ws + off); off += (size_t)BB * NN * 64 * 4;
    float* stats = (float*)(ws + off);  // 128 floats: sum[64], sumsq[64]

    hipLaunchKernelGGL(zero_stats_kernel, dim3(1), dim3(128), 0, stream, stats);
    hipLaunchKernelGGL(qkv_kernel, dim3(512), dim3(256), 0, stream,
                       feats, Wq, Wk, Wv, Q, Kf, Vf);
    hipLaunchKernelGGL(knn_chunk_kernel, dim3(BB * (NN / 64) * nchunk), dim3(64), 0, stream,
                       xyz, partial, nchunk);
    hipLaunchKernelGGL(knn_merge_kernel, dim3(BB * NN / 256), dim3(256), 0, stream,
                       partial, knn, nchunk);
    hipLaunchKernelGGL(attn_kernel, dim3(512), dim3(256), 0, stream,
                       xyz, feats, Q, Kf, Vf, knn,
                       d1w, d1b, d2w, d2b, g1w, g1b, g2w, g2b,
                       out, stats, stats + 64);
    hipLaunchKernelGGL(bn_final_kernel, dim3(512), dim3(256), 0, stream,
                       out, stats, stats + 64, bnw, bnb);
}

// Round 2
// 417.301 us; speedup vs baseline: 2.1980x; 2.1980x over previous
//
#include <hip/hip_runtime.h>
#include <hip/hip_bf16.h>

#define BB 8
#define NN 4096
#define DD 64

typedef __attribute__((ext_vector_type(8))) short short8;
typedef __attribute__((ext_vector_type(4))) float f32x4;

__device__ __forceinline__ short f2bf(float f) {
    __hip_bfloat16 h = __float2bfloat16(f);
    return __builtin_bit_cast(short, h);
}

__device__ __forceinline__ float bcastf(float x, int l) {
    return __int_as_float(__builtin_amdgcn_readlane(__float_as_int(x), l));
}

// ---------------- exact kNN: wave = 1 query ----------------
__device__ __forceinline__ void bsort64(float& d, int& i, int lane) {
#pragma unroll
    for (int s = 2; s <= 64; s <<= 1) {
#pragma unroll
        for (int m = s >> 1; m >= 1; m >>= 1) {
            float dp = __shfl_xor(d, m);
            int ip = __shfl_xor(i, m);
            bool up = ((lane & s) == 0);
            bool lower = ((lane & m) == 0);
            bool less = (d < dp) || (d == dp && i < ip);
            bool takeMine = (less == (up == lower));
            d = takeMine ? d : dp;
            i = takeMine ? i : ip;
        }
    }
}

__device__ __forceinline__ float pdist(const float* X, int c, float qx, float qy,
                                       float qz, float sqq) {
    float cx = X[c * 3], cy = X[c * 3 + 1], cz = X[c * 3 + 2];
    float sqc = __fadd_rn(__fadd_rn(__fmul_rn(cx, cx), __fmul_rn(cy, cy)), __fmul_rn(cz, cz));
    float dot = __fadd_rn(__fadd_rn(__fmul_rn(qx, cx), __fmul_rn(qy, cy)), __fmul_rn(qz, cz));
    return __fadd_rn(__fadd_rn(sqq, sqc), -__fmul_rn(2.0f, dot));
}

__global__ __launch_bounds__(256) void knn_kernel(const float* __restrict__ xyz,
                                                  int* __restrict__ knnIdx) {
    __shared__ __align__(16) float X[NN * 3];
    __shared__ float bufD[4][64];
    __shared__ int bufI[4][64];
    int tid = threadIdx.x;
    int b = blockIdx.x >> 6;       // 64 blocks per batch
    int qgroup = blockIdx.x & 63;  // 64 queries per block
    const float* xb = xyz + (size_t)b * NN * 3;
    for (int i = tid; i < NN * 3 / 4; i += 256)
        ((float4*)X)[i] = ((const float4*)xb)[i];
    __syncthreads();

    int wid = tid >> 6, lane = tid & 63;
    float* bD = bufD[wid];
    int* bI = bufI[wid];

    for (int qi = 0; qi < 16; ++qi) {
        int qq = qgroup * 64 + wid * 16 + qi;
        float qx = X[qq * 3], qy = X[qq * 3 + 1], qz = X[qq * 3 + 2];
        float sqq = __fadd_rn(__fadd_rn(__fmul_rn(qx, qx), __fmul_rn(qy, qy)),
                              __fmul_rn(qz, qz));
        // round 0: candidates 0..63
        float d0 = pdist(X, lane, qx, qy, qz, sqq);
        int i0 = lane;
        bsort64(d0, i0, lane);
        if (lane < 16) { bD[lane] = d0; bI[lane] = i0; }
        int count = 16;
        float t = __shfl(d0, 15);

        for (int r = 1; r < 64; ++r) {
            int cidx = r * 64 + lane;
            float dc = pdist(X, cidx, qx, qy, qz, sqq);
            unsigned long long mask = __ballot(dc < t);
            while (mask) {
                int avail = 64 - count;
                unsigned long long below = mask & ((1ull << lane) - 1ull);
                int pos = __popcll(below);
                bool mine = (mask >> lane) & 1;
                if (mine && pos < avail) {
                    bD[count + pos] = dc;
                    bI[count + pos] = cidx;
                }
                int nq = __popcll(mask);
                if (nq <= avail) {
                    count += nq;
                    mask = 0;
                } else {
                    count = 64;
                    mask = __ballot(mine && pos >= avail);
                    // sort-cut to exact top-16 of all seen so far
                    float sd = (lane < count) ? bD[lane] : 3.0e38f;
                    int si = (lane < count) ? bI[lane] : 0x7fffffff;
                    bsort64(sd, si, lane);
                    if (lane < 16) { bD[lane] = sd; bI[lane] = si; }
                    count = 16;
                    t = __shfl(sd, 15);
                    mask &= __ballot(dc < t);
                }
            }
        }
        float fd = (lane < count) ? bD[lane] : 3.0e38f;
        int fi = (lane < count) ? bI[lane] : 0x7fffffff;
        bsort64(fd, fi, lane);
        if (lane < 16) knnIdx[((size_t)b * NN + qq) * 16 + lane] = fi;
    }
}

// ---------------- q/k/v projections (f32, readlane broadcast) ----------------
__global__ __launch_bounds__(256) void qkv_kernel(const float* __restrict__ feats,
                                                  const float* __restrict__ Wq,
                                                  const float* __restrict__ Wk,
                                                  const float* __restrict__ Wv,
                                                  float* __restrict__ Q,
                                                  float* __restrict__ Kf,
                                                  float* __restrict__ Vf) {
    __shared__ float Aq[4096], Ak[4096], Av[4096];
    int tid = threadIdx.x;
    for (int i = tid; i < 4096; i += 256) { Aq[i] = Wq[i]; Ak[i] = Wk[i]; Av[i] = Wv[i]; }
    __syncthreads();
    int lane = tid & 63, wid = tid >> 6;
    int gw = blockIdx.x * 4 + wid, nw = gridDim.x * 4;
    for (int r = gw; r < BB * NN; r += nw) {
        float f = feats[(size_t)r * 64 + lane];
        float aq = 0.f, ak = 0.f, av = 0.f;
#pragma unroll 8
        for (int h = 0; h < 64; ++h) {
            float s = bcastf(f, h);
            aq = fmaf(s, Aq[h * 64 + lane], aq);
            ak = fmaf(s, Ak[h * 64 + lane], ak);
            av = fmaf(s, Av[h * 64 + lane], av);
        }
        Q[(size_t)r * 64 + lane] = aq;
        Kf[(size_t)r * 64 + lane] = ak;
        Vf[(size_t)r * 64 + lane] = av;
    }
}

// ---------------- fused MFMA attention: wave = 1 point ----------------
// A-layout (16x16x32 bf16): lane holds A[row=l&15][k=(l>>4)*8+j]
// B-layout: lane holds B[k=(l>>4)*8+j][col=l&15]
// C-layout: lane holds C[row=(l>>4)*4+r][col=l&15]
#define TSTR 68  // padded LDS transpose row stride (floats); 68*4B = 272B, 16B aligned

__global__ __launch_bounds__(256, 2) void attn_kernel(
    const float* __restrict__ xyz, const float* __restrict__ feats,
    const float* __restrict__ Q, const float* __restrict__ Kf, const float* __restrict__ Vf,
    const int* __restrict__ knnIdx,
    const float* __restrict__ d1w, const float* __restrict__ d1b,
    const float* __restrict__ d2w, const float* __restrict__ d2b,
    const float* __restrict__ g1w, const float* __restrict__ g1b,
    const float* __restrict__ g2w, const float* __restrict__ g2b,
    float* __restrict__ out, float* __restrict__ gsum, float* __restrict__ gsq) {
    __shared__ float d1s[4][64];             // w0,w1,w2,b1 rows
    __shared__ __align__(16) float tbuf[4][16 * TSTR];
    __shared__ float bns[64], bnq[64];
    int tid = threadIdx.x;
    if (tid < 256) {
        int a = tid >> 6, ch = tid & 63;
        d1s[a][ch] = (a < 3) ? d1w[a * 64 + ch] : d1b[ch];
    }
    if (tid < 64) { bns[tid] = 0.f; bnq[tid] = 0.f; }
    __syncthreads();

    int lane = tid & 63, wid = tid >> 6;
    int cc = lane & 15, g = lane >> 4;
    float* tb = tbuf[wid];

    // --- preload B-fragments (bf16) for d2w, g1w, g2w ---
    short8 bd2[2][4], bg1[2][4], bg2[2][4];
#pragma unroll
    for (int kt = 0; kt < 2; ++kt)
#pragma unroll
        for (int ct = 0; ct < 4; ++ct) {
            short8 f2, fg1, fg2;
#pragma unroll
            for (int j = 0; j < 8; ++j) {
                int kk = kt * 32 + g * 8 + j, col = ct * 16 + cc;
                f2[j] = f2bf(d2w[kk * 64 + col]);
                fg1[j] = f2bf(g1w[kk * 64 + col]);
                fg2[j] = f2bf(g2w[kk * 64 + col]);
            }
            bd2[kt][ct] = f2; bg1[kt][ct] = fg1; bg2[kt][ct] = fg2;
        }
    float b2c[4], gb1c[4], gb2c[4];
#pragma unroll
    for (int ct = 0; ct < 4; ++ct) {
        b2c[ct] = d2b[ct * 16 + cc];
        gb1c[ct] = g1b[ct * 16 + cc];
        gb2c[ct] = g2b[ct * 16 + cc];
    }
    bool is1 = (g == 1), is2 = (g == 2), is3 = (g == 3);

    int gw = blockIdx.x * 4 + wid, nw = gridDim.x * 4;
    float lsum = 0.f, lsq = 0.f;

    for (int p = gw; p < BB * NN; p += nw) {
        int b = p >> 12;
        int idxA = knnIdx[(size_t)p * 16 + cc];
        int nb = (b << 12) + idxA;

        // gathers (A-layout channel blocks: g*8..g*8+7 and 32+g*8..)
        const float* Qp = Q + (size_t)p * 64;
        const float* Kp = Kf + (size_t)nb * 64;
        f32x4 q0 = *(const f32x4*)&Qp[g * 8], q1 = *(const f32x4*)&Qp[g * 8 + 4];
        f32x4 q2 = *(const f32x4*)&Qp[32 + g * 8], q3 = *(const f32x4*)&Qp[32 + g * 8 + 4];
        f32x4 k0 = *(const f32x4*)&Kp[g * 8], k1 = *(const f32x4*)&Kp[g * 8 + 4];
        f32x4 k2 = *(const f32x4*)&Kp[32 + g * 8], k3 = *(const f32x4*)&Kp[32 + g * 8 + 4];

        float sx = xyz[(size_t)p * 3], sy = xyz[(size_t)p * 3 + 1], sz = xyz[(size_t)p * 3 + 2];
        float dx = sx - xyz[(size_t)nb * 3];
        float dy = sy - xyz[(size_t)nb * 3 + 1];
        float dz = sz - xyz[(size_t)nb * 3 + 2];

        // --- H = relu(delta @ d1 + b1), built directly in A-layout ---
        short8 ha[2];
#pragma unroll
        for (int kt = 0; kt < 2; ++kt) {
            short8 hv;
#pragma unroll
            for (int hb = 0; hb < 2; ++hb) {
                int ch = kt * 32 + g * 8 + hb * 4;
                f32x4 w0 = *(const f32x4*)&d1s[0][ch];
                f32x4 w1 = *(const f32x4*)&d1s[1][ch];
                f32x4 w2 = *(const f32x4*)&d1s[2][ch];
                f32x4 bb_ = *(const f32x4*)&d1s[3][ch];
#pragma unroll
                for (int j = 0; j < 4; ++j) {
                    float h = bb_[j] + dx * w0[j] + dy * w1[j] + dz * w2[j];
                    hv[hb * 4 + j] = f2bf(fmaxf(h, 0.f));
                }
            }
            ha[kt] = hv;
        }

        // --- mm1: pe = H @ d2w + b2 (C-layout) ---
        f32x4 pe[4];
#pragma unroll
        for (int ct = 0; ct < 4; ++ct) {
            f32x4 acc = {0.f, 0.f, 0.f, 0.f};
            acc = __builtin_amdgcn_mfma_f32_16x16x32_bf16(ha[0], bd2[0][ct], acc, 0, 0, 0);
            acc = __builtin_amdgcn_mfma_f32_16x16x32_bf16(ha[1], bd2[1][ct], acc, 0, 0, 0);
#pragma unroll
            for (int r = 0; r < 4; ++r) pe[ct][r] = acc[r] + b2c[ct];
        }

        // --- T1: transpose pe C->A; x = q - k + pe -> bf16 ---
#pragma unroll
        for (int ct = 0; ct < 4; ++ct)
#pragma unroll
            for (int r = 0; r < 4; ++r)
                tb[(4 * g + r) * TSTR + ct * 16 + cc] = pe[ct][r];
        short8 xa[2];
        {
            f32x4 p0 = *(const f32x4*)&tb[cc * TSTR + g * 8];
            f32x4 p1 = *(const f32x4*)&tb[cc * TSTR + g * 8 + 4];
            f32x4 p2 = *(const f32x4*)&tb[cc * TSTR + 32 + g * 8];
            f32x4 p3 = *(const f32x4*)&tb[cc * TSTR + 32 + g * 8 + 4];
            f32x4 x0 = q0 - k0 + p0, x1 = q1 - k1 + p1;
            f32x4 x2 = q2 - k2 + p2, x3 = q3 - k3 + p3;
            short8 v0, v1;
#pragma unroll
            for (int j = 0; j < 4; ++j) {
                v0[j] = f2bf(x0[j]); v0[4 + j] = f2bf(x1[j]);
                v1[j] = f2bf(x2[j]); v1[4 + j] = f2bf(x3[j]);
            }
            xa[0] = v0; xa[1] = v1;
        }

        // --- mm2: h2 = relu(x @ g1w + gb1) (C-layout) ---
        f32x4 h2[4];
#pragma unroll
        for (int ct = 0; ct < 4; ++ct) {
            f32x4 acc = {0.f, 0.f, 0.f, 0.f};
            acc = __builtin_amdgcn_mfma_f32_16x16x32_bf16(xa[0], bg1[0][ct], acc, 0, 0, 0);
            acc = __builtin_amdgcn_mfma_f32_16x16x32_bf16(xa[1], bg1[1][ct], acc, 0, 0, 0);
#pragma unroll
            for (int r = 0; r < 4; ++r) h2[ct][r] = fmaxf(acc[r] + gb1c[ct], 0.f);
        }

        // --- T3: transpose h2 C->A -> bf16 ---
#pragma unroll
        for (int ct = 0; ct < 4; ++ct)
#pragma unroll
            for (int r = 0; r < 4; ++r)
                tb[(4 * g + r) * TSTR + ct * 16 + cc] = h2[ct][r];
        short8 h2a[2];
        {
            f32x4 p0 = *(const f32x4*)&tb[cc * TSTR + g * 8];
            f32x4 p1 = *(const f32x4*)&tb[cc * TSTR + g * 8 + 4];
            f32x4 p2 = *(const f32x4*)&tb[cc * TSTR + 32 + g * 8];
            f32x4 p3 = *(const f32x4*)&tb[cc * TSTR + 32 + g * 8 + 4];
            short8 v0, v1;
#pragma unroll
            for (int j = 0; j < 4; ++j) {
                v0[j] = f2bf(p0[j]); v0[4 + j] = f2bf(p1[j]);
                v1[j] = f2bf(p2[j]); v1[4 + j] = f2bf(p3[j]);
            }
            h2a[0] = v0; h2a[1] = v1;
        }

        // --- mm3: logits = h2 @ g2w + gb2 (C-layout) ---
        f32x4 lg[4];
#pragma unroll
        for (int ct = 0; ct < 4; ++ct) {
            f32x4 acc = {0.f, 0.f, 0.f, 0.f};
            acc = __builtin_amdgcn_mfma_f32_16x16x32_bf16(h2a[0], bg2[0][ct], acc, 0, 0, 0);
            acc = __builtin_amdgcn_mfma_f32_16x16x32_bf16(h2a[1], bg2[1][ct], acc, 0, 0, 0);
#pragma unroll
            for (int r = 0; r < 4; ++r) lg[ct][r] = acc[r] + gb2c[ct];
        }

        // --- T2: gather v (A-layout) -> transpose to C-layout ---
        const float* Vp = Vf + (size_t)nb * 64;
        {
            f32x4 v0 = *(const f32x4*)&Vp[g * 8], v1 = *(const f32x4*)&Vp[g * 8 + 4];
            f32x4 v2 = *(const f32x4*)&Vp[32 + g * 8], v3 = *(const f32x4*)&Vp[32 + g * 8 + 4];
            *(f32x4*)&tb[cc * TSTR + g * 8] = v0;
            *(f32x4*)&tb[cc * TSTR + g * 8 + 4] = v1;
            *(f32x4*)&tb[cc * TSTR + 32 + g * 8] = v2;
            *(f32x4*)&tb[cc * TSTR + 32 + g * 8 + 4] = v3;
        }
        f32x4 vc[4];
#pragma unroll
        for (int ct = 0; ct < 4; ++ct)
#pragma unroll
            for (int r = 0; r < 4; ++r)
                vc[ct][r] = tb[(4 * g + r) * TSTR + ct * 16 + cc];

        // --- softmax over k (rows) + weighted sum ---
        float part[4];
#pragma unroll
        for (int ct = 0; ct < 4; ++ct) {
            float m = fmaxf(fmaxf(lg[ct][0], lg[ct][1]), fmaxf(lg[ct][2], lg[ct][3]));
            m = fmaxf(m, __shfl_xor(m, 16));
            m = fmaxf(m, __shfl_xor(m, 32));
            float e0 = __expf(lg[ct][0] - m), e1 = __expf(lg[ct][1] - m);
            float e2 = __expf(lg[ct][2] - m), e3 = __expf(lg[ct][3] - m);
            float s = e0 + e1 + e2 + e3;
            s += __shfl_xor(s, 16);
            s += __shfl_xor(s, 32);
            float inv = 1.0f / s;
            float pt = 0.f;
            pt = fmaf(e0 * inv, vc[ct][0] + pe[ct][0], pt);
            pt = fmaf(e1 * inv, vc[ct][1] + pe[ct][1], pt);
            pt = fmaf(e2 * inv, vc[ct][2] + pe[ct][2], pt);
            pt = fmaf(e3 * inv, vc[ct][3] + pe[ct][3], pt);
            pt += __shfl_xor(pt, 16);
            pt += __shfl_xor(pt, 32);
            part[ct] = pt;
        }
        float resv = part[0];
        resv = is1 ? part[1] : resv;
        resv = is2 ? part[2] : resv;
        resv = is3 ? part[3] : resv;
        resv += feats[(size_t)p * 64 + lane];
        out[(size_t)p * 64 + lane] = resv;
        lsum += resv;
        lsq = fmaf(resv, resv, lsq);
    }
    atomicAdd(&bns[lane], lsum);
    atomicAdd(&bnq[lane], lsq);
    __syncthreads();
    if (tid < 64) {
        atomicAdd(&gsum[tid], bns[tid]);
        atomicAdd(&gsq[tid], bnq[tid]);
    }
}

// ---------------- stats zero + BatchNorm finalize ----------------
__global__ void zero_stats_kernel(float* s) {
    if (threadIdx.x < 128) s[threadIdx.x] = 0.f;
}

__global__ __launch_bounds__(256) void bn_final_kernel(float* __restrict__ out,
                                                       const float* __restrict__ gsum,
                                                       const float* __restrict__ gsq,
                                                       const float* __restrict__ bnw,
                                                       const float* __restrict__ bnb) {
    __shared__ float sc[64], sh[64];
    int tid = threadIdx.x;
    if (tid < 64) {
        const float invN = 1.0f / (float)(BB * NN);
        float mean = gsum[tid] * invN;
        float var = gsq[tid] * invN - mean * mean;
        float inv = rsqrtf(var + 1e-5f);
        float scale = inv * bnw[tid];
        sc[tid] = scale;
        sh[tid] = bnb[tid] - mean * scale;
    }
    __syncthreads();
    size_t total = (size_t)BB * NN * 64;
    for (size_t i = (size_t)blockIdx.x * 256 + tid; i < total; i += (size_t)gridDim.x * 256) {
        int c = (int)(i & 63);
        out[i] = fmaf(out[i], sc[c], sh[c]);
    }
}

extern "C" void kernel_launch(void* const* d_in, const int* in_sizes, int n_in,
                              void* d_out, int out_size, void* d_ws, size_t ws_size,
                              hipStream_t stream) {
    const float* xyz = (const float*)d_in[0];
    const float* feats = (const float*)d_in[1];
    const float* Wq = (const float*)d_in[2];
    const float* Wk = (const float*)d_in[3];
    const float* Wv = (const float*)d_in[4];
    const float* d1w = (const float*)d_in[5];
    const float* d1b = (const float*)d_in[6];
    const float* d2w = (const float*)d_in[7];
    const float* d2b = (const float*)d_in[8];
    const float* g1w = (const float*)d_in[9];
    const float* g1b = (const float*)d_in[10];
    const float* g2w = (const float*)d_in[11];
    const float* g2b = (const float*)d_in[12];
    const float* bnw = (const float*)d_in[13];
    const float* bnb = (const float*)d_in[14];
    float* out = (float*)d_out;

    char* ws = (char*)d_ws;
    size_t off = 0;
    int* knnIdx = (int*)(ws + off); off += (size_t)BB * NN * 16 * 4;
    float* Q = (float*)(ws + off); off += (size_t)BB * NN * 64 * 4;
    float* Kf = (float*)(ws + off); off += (size_t)BB * NN * 64 * 4;
    float* Vf = (float*)(ws + off); off += (size_t)BB * NN * 64 * 4;
    float* stats = (float*)(ws + off);  // 128 floats

    hipLaunchKernelGGL(zero_stats_kernel, dim3(1), dim3(128), 0, stream, stats);
    hipLaunchKernelGGL(qkv_kernel, dim3(512), dim3(256), 0, stream,
                       feats, Wq, Wk, Wv, Q, Kf, Vf);
    hipLaunchKernelGGL(knn_kernel, dim3(BB * 64), dim3(256), 0, stream, xyz, knnIdx);
    hipLaunchKernelGGL(attn_kernel, dim3(512), dim3(256), 0, stream,
                       xyz, feats, Q, Kf, Vf, knnIdx,
                       d1w, d1b, d2w, d2b, g1w, g1b, g2w, g2b,
                       out, stats, stats + 64);
    hipLaunchKernelGGL(bn_final_kernel, dim3(512), dim3(256), 0, stream,
                       out, stats, stats + 64, bnw, bnb);
}

// Round 4
// 350.300 us; speedup vs baseline: 2.6184x; 1.1913x over previous
//
#include <hip/hip_runtime.h>
#include <hip/hip_bf16.h>

#define BB 8
#define NN 4096
#define DD 64

typedef __attribute__((ext_vector_type(8))) short short8;
typedef __attribute__((ext_vector_type(4))) float f32x4;

__device__ __forceinline__ short f2bf(float f) {
    __hip_bfloat16 h = __float2bfloat16(f);
    return __builtin_bit_cast(short, h);
}

__device__ __forceinline__ float bcastf(float x, int l) {
    return __int_as_float(__builtin_amdgcn_readlane(__float_as_int(x), l));
}

// ---------------- exact kNN: wave = 1 query (round-2 proven logic) ----------------
__device__ __forceinline__ void bsort64(float& d, int& i, int lane) {
#pragma unroll
    for (int s = 2; s <= 64; s <<= 1) {
#pragma unroll
        for (int m = s >> 1; m >= 1; m >>= 1) {
            float dp = __shfl_xor(d, m);
            int ip = __shfl_xor(i, m);
            bool up = ((lane & s) == 0);
            bool lower = ((lane & m) == 0);
            bool less = (d < dp) || (d == dp && i < ip);
            bool takeMine = (less == (up == lower));
            d = takeMine ? d : dp;
            i = takeMine ? i : ip;
        }
    }
}

__device__ __forceinline__ float pdist(const float* X, int c, float qx, float qy,
                                       float qz, float sqq) {
    float cx = X[c * 3], cy = X[c * 3 + 1], cz = X[c * 3 + 2];
    float sqc = __fadd_rn(__fadd_rn(__fmul_rn(cx, cx), __fmul_rn(cy, cy)), __fmul_rn(cz, cz));
    float dot = __fadd_rn(__fadd_rn(__fmul_rn(qx, cx), __fmul_rn(qy, cy)), __fmul_rn(qz, cz));
    return __fadd_rn(__fadd_rn(sqq, sqc), -__fmul_rn(2.0f, dot));
}

// block = 256 threads = 4 waves; 16 queries per block (4 per wave) -> grid 2048
__global__ __launch_bounds__(256) void knn_kernel(const float* __restrict__ xyz,
                                                  int* __restrict__ knnIdx) {
    __shared__ __align__(16) float X[NN * 3];
    __shared__ float bufD[4][64];
    __shared__ int bufI[4][64];
    int tid = threadIdx.x;
    int b = blockIdx.x >> 8;        // 256 blocks per batch
    int qgroup = blockIdx.x & 255;  // 16 queries per block
    const float* xb = xyz + (size_t)b * NN * 3;
    for (int i = tid; i < NN * 3 / 4; i += 256)
        ((float4*)X)[i] = ((const float4*)xb)[i];
    __syncthreads();

    int wid = tid >> 6, lane = tid & 63;
    float* bD = bufD[wid];
    int* bI = bufI[wid];

    for (int qi = 0; qi < 4; ++qi) {
        int qq = qgroup * 16 + wid * 4 + qi;
        float qx = X[qq * 3], qy = X[qq * 3 + 1], qz = X[qq * 3 + 2];
        float sqq = __fadd_rn(__fadd_rn(__fmul_rn(qx, qx), __fmul_rn(qy, qy)),
                              __fmul_rn(qz, qz));
        // round 0: candidates 0..63
        float d0 = pdist(X, lane, qx, qy, qz, sqq);
        int i0 = lane;
        bsort64(d0, i0, lane);
        if (lane < 16) { bD[lane] = d0; bI[lane] = i0; }
        int count = 16;
        float t = __shfl(d0, 15);

        for (int r = 1; r < 64; ++r) {
            int cidx = r * 64 + lane;
            float dc = pdist(X, cidx, qx, qy, qz, sqq);
            unsigned long long mask = __ballot(dc < t);
            while (mask) {
                int avail = 64 - count;
                unsigned long long below = mask & ((1ull << lane) - 1ull);
                int pos = __popcll(below);
                bool mine = (mask >> lane) & 1;
                if (mine && pos < avail) {
                    bD[count + pos] = dc;
                    bI[count + pos] = cidx;
                }
                int nq = __popcll(mask);
                if (nq <= avail) {
                    count += nq;
                    mask = 0;
                } else {
                    count = 64;
                    mask = __ballot(mine && pos >= avail);
                    // sort-cut to exact top-16 of all seen so far
                    float sd = (lane < count) ? bD[lane] : 3.0e38f;
                    int si = (lane < count) ? bI[lane] : 0x7fffffff;
                    bsort64(sd, si, lane);
                    if (lane < 16) { bD[lane] = sd; bI[lane] = si; }
                    count = 16;
                    t = __shfl(sd, 15);
                    mask &= __ballot(dc < t);
                }
            }
        }
        float fd = (lane < count) ? bD[lane] : 3.0e38f;
        int fi = (lane < count) ? bI[lane] : 0x7fffffff;
        bsort64(fd, fi, lane);
        if (lane < 16) knnIdx[((size_t)b * NN + qq) * 16 + lane] = fi;
    }
}

// ---------------- q/k/v projections (f32, readlane broadcast) ----------------
__global__ __launch_bounds__(256) void qkv_kernel(const float* __restrict__ feats,
                                                  const float* __restrict__ Wq,
                                                  const float* __restrict__ Wk,
                                                  const float* __restrict__ Wv,
                                                  float* __restrict__ Q,
                                                  float* __restrict__ Kf,
                                                  float* __restrict__ Vf) {
    __shared__ float Aq[4096], Ak[4096], Av[4096];
    int tid = threadIdx.x;
    for (int i = tid; i < 4096; i += 256) { Aq[i] = Wq[i]; Ak[i] = Wk[i]; Av[i] = Wv[i]; }
    __syncthreads();
    int lane = tid & 63, wid = tid >> 6;
    int gw = blockIdx.x * 4 + wid, nw = gridDim.x * 4;
    for (int r = gw; r < BB * NN; r += nw) {
        float f = feats[(size_t)r * 64 + lane];
        float aq = 0.f, ak = 0.f, av = 0.f;
#pragma unroll 8
        for (int h = 0; h < 64; ++h) {
            float s = bcastf(f, h);
            aq = fmaf(s, Aq[h * 64 + lane], aq);
            ak = fmaf(s, Ak[h * 64 + lane], ak);
            av = fmaf(s, Av[h * 64 + lane], av);
        }
        Q[(size_t)r * 64 + lane] = aq;
        Kf[(size_t)r * 64 + lane] = ak;
        Vf[(size_t)r * 64 + lane] = av;
    }
}

// ---------------- fused MFMA attention: wave = 1 point ----------------
#define TSTR 68

__global__ __launch_bounds__(256, 2) void attn_kernel(
    const float* __restrict__ xyz, const float* __restrict__ feats,
    const float* __restrict__ Q, const float* __restrict__ Kf, const float* __restrict__ Vf,
    const int* __restrict__ knnIdx,
    const float* __restrict__ d1w, const float* __restrict__ d1b,
    const float* __restrict__ d2w, const float* __restrict__ d2b,
    const float* __restrict__ g1w, const float* __restrict__ g1b,
    const float* __restrict__ g2w, const float* __restrict__ g2b,
    float* __restrict__ out, float* __restrict__ gsum, float* __restrict__ gsq) {
    __shared__ float d1s[4][64];
    __shared__ __align__(16) float tbuf[4][16 * TSTR];
    __shared__ float bns[64], bnq[64];
    int tid = threadIdx.x;
    if (tid < 256) {
        int a = tid >> 6, ch = tid & 63;
        d1s[a][ch] = (a < 3) ? d1w[a * 64 + ch] : d1b[ch];
    }
    if (tid < 64) { bns[tid] = 0.f; bnq[tid] = 0.f; }
    __syncthreads();

    int lane = tid & 63, wid = tid >> 6;
    int cc = lane & 15, g = lane >> 4;
    float* tb = tbuf[wid];

    short8 bd2[2][4], bg1[2][4], bg2[2][4];
#pragma unroll
    for (int kt = 0; kt < 2; ++kt)
#pragma unroll
        for (int ct = 0; ct < 4; ++ct) {
            short8 f2, fg1, fg2;
#pragma unroll
            for (int j = 0; j < 8; ++j) {
                int kk = kt * 32 + g * 8 + j, col = ct * 16 + cc;
                f2[j] = f2bf(d2w[kk * 64 + col]);
                fg1[j] = f2bf(g1w[kk * 64 + col]);
                fg2[j] = f2bf(g2w[kk * 64 + col]);
            }
            bd2[kt][ct] = f2; bg1[kt][ct] = fg1; bg2[kt][ct] = fg2;
        }
    float b2c[4], gb1c[4], gb2c[4];
#pragma unroll
    for (int ct = 0; ct < 4; ++ct) {
        b2c[ct] = d2b[ct * 16 + cc];
        gb1c[ct] = g1b[ct * 16 + cc];
        gb2c[ct] = g2b[ct * 16 + cc];
    }
    bool is1 = (g == 1), is2 = (g == 2), is3 = (g == 3);

    int gw = blockIdx.x * 4 + wid, nw = gridDim.x * 4;
    float lsum = 0.f, lsq = 0.f;

    for (int p = gw; p < BB * NN; p += nw) {
        int b = p >> 12;
        int idxA = knnIdx[(size_t)p * 16 + cc];
        int nb = (b << 12) + idxA;

        const float* Qp = Q + (size_t)p * 64;
        const float* Kp = Kf + (size_t)nb * 64;
        f32x4 q0 = *(const f32x4*)&Qp[g * 8], q1 = *(const f32x4*)&Qp[g * 8 + 4];
        f32x4 q2 = *(const f32x4*)&Qp[32 + g * 8], q3 = *(const f32x4*)&Qp[32 + g * 8 + 4];
        f32x4 k0 = *(const f32x4*)&Kp[g * 8], k1 = *(const f32x4*)&Kp[g * 8 + 4];
        f32x4 k2 = *(const f32x4*)&Kp[32 + g * 8], k3 = *(const f32x4*)&Kp[32 + g * 8 + 4];

        float sx = xyz[(size_t)p * 3], sy = xyz[(size_t)p * 3 + 1], sz = xyz[(size_t)p * 3 + 2];
        float dx = sx - xyz[(size_t)nb * 3];
        float dy = sy - xyz[(size_t)nb * 3 + 1];
        float dz = sz - xyz[(size_t)nb * 3 + 2];

        short8 ha[2];
#pragma unroll
        for (int kt = 0; kt < 2; ++kt) {
            short8 hv;
#pragma unroll
            for (int hb = 0; hb < 2; ++hb) {
                int ch = kt * 32 + g * 8 + hb * 4;
                f32x4 w0 = *(const f32x4*)&d1s[0][ch];
                f32x4 w1 = *(const f32x4*)&d1s[1][ch];
                f32x4 w2 = *(const f32x4*)&d1s[2][ch];
                f32x4 bb_ = *(const f32x4*)&d1s[3][ch];
#pragma unroll
                for (int j = 0; j < 4; ++j) {
                    float h = bb_[j] + dx * w0[j] + dy * w1[j] + dz * w2[j];
                    hv[hb * 4 + j] = f2bf(fmaxf(h, 0.f));
                }
            }
            ha[kt] = hv;
        }

        f32x4 pe[4];
#pragma unroll
        for (int ct = 0; ct < 4; ++ct) {
            f32x4 acc = {0.f, 0.f, 0.f, 0.f};
            acc = __builtin_amdgcn_mfma_f32_16x16x32_bf16(ha[0], bd2[0][ct], acc, 0, 0, 0);
            acc = __builtin_amdgcn_mfma_f32_16x16x32_bf16(ha[1], bd2[1][ct], acc, 0, 0, 0);
#pragma unroll
            for (int r = 0; r < 4; ++r) pe[ct][r] = acc[r] + b2c[ct];
        }

#pragma unroll
        for (int ct = 0; ct < 4; ++ct)
#pragma unroll
            for (int r = 0; r < 4; ++r)
                tb[(4 * g + r) * TSTR + ct * 16 + cc] = pe[ct][r];
        short8 xa[2];
        {
            f32x4 p0 = *(const f32x4*)&tb[cc * TSTR + g * 8];
            f32x4 p1 = *(const f32x4*)&tb[cc * TSTR + g * 8 + 4];
            f32x4 p2 = *(const f32x4*)&tb[cc * TSTR + 32 + g * 8];
            f32x4 p3 = *(const f32x4*)&tb[cc * TSTR + 32 + g * 8 + 4];
            f32x4 x0 = q0 - k0 + p0, x1 = q1 - k1 + p1;
            f32x4 x2 = q2 - k2 + p2, x3 = q3 - k3 + p3;
            short8 v0, v1;
#pragma unroll
            for (int j = 0; j < 4; ++j) {
                v0[j] = f2bf(x0[j]); v0[4 + j] = f2bf(x1[j]);
                v1[j] = f2bf(x2[j]); v1[4 + j] = f2bf(x3[j]);
            }
            xa[0] = v0; xa[1] = v1;
        }

        f32x4 h2[4];
#pragma unroll
        for (int ct = 0; ct < 4; ++ct) {
            f32x4 acc = {0.f, 0.f, 0.f, 0.f};
            acc = __builtin_amdgcn_mfma_f32_16x16x32_bf16(xa[0], bg1[0][ct], acc, 0, 0, 0);
            acc = __builtin_amdgcn_mfma_f32_16x16x32_bf16(xa[1], bg1[1][ct], acc, 0, 0, 0);
#pragma unroll
            for (int r = 0; r < 4; ++r) h2[ct][r] = fmaxf(acc[r] + gb1c[ct], 0.f);
        }

#pragma unroll
        for (int ct = 0; ct < 4; ++ct)
#pragma unroll
            for (int r = 0; r < 4; ++r)
                tb[(4 * g + r) * TSTR + ct * 16 + cc] = h2[ct][r];
        short8 h2a[2];
        {
            f32x4 p0 = *(const f32x4*)&tb[cc * TSTR + g * 8];
            f32x4 p1 = *(const f32x4*)&tb[cc * TSTR + g * 8 + 4];
            f32x4 p2 = *(const f32x4*)&tb[cc * TSTR + 32 + g * 8];
            f32x4 p3 = *(const f32x4*)&tb[cc * TSTR + 32 + g * 8 + 4];
            short8 v0, v1;
#pragma unroll
            for (int j = 0; j < 4; ++j) {
                v0[j] = f2bf(p0[j]); v0[4 + j] = f2bf(p1[j]);
                v1[j] = f2bf(p2[j]); v1[4 + j] = f2bf(p3[j]);
            }
            h2a[0] = v0; h2a[1] = v1;
        }

        f32x4 lg[4];
#pragma unroll
        for (int ct = 0; ct < 4; ++ct) {
            f32x4 acc = {0.f, 0.f, 0.f, 0.f};
            acc = __builtin_amdgcn_mfma_f32_16x16x32_bf16(h2a[0], bg2[0][ct], acc, 0, 0, 0);
            acc = __builtin_amdgcn_mfma_f32_16x16x32_bf16(h2a[1], bg2[1][ct], acc, 0, 0, 0);
#pragma unroll
            for (int r = 0; r < 4; ++r) lg[ct][r] = acc[r] + gb2c[ct];
        }

        const float* Vp = Vf + (size_t)nb * 64;
        {
            f32x4 v0 = *(const f32x4*)&Vp[g * 8], v1 = *(const f32x4*)&Vp[g * 8 + 4];
            f32x4 v2 = *(const f32x4*)&Vp[32 + g * 8], v3 = *(const f32x4*)&Vp[32 + g * 8 + 4];
            *(f32x4*)&tb[cc * TSTR + g * 8] = v0;
            *(f32x4*)&tb[cc * TSTR + g * 8 + 4] = v1;
            *(f32x4*)&tb[cc * TSTR + 32 + g * 8] = v2;
            *(f32x4*)&tb[cc * TSTR + 32 + g * 8 + 4] = v3;
        }
        f32x4 vc[4];
#pragma unroll
        for (int ct = 0; ct < 4; ++ct)
#pragma unroll
            for (int r = 0; r < 4; ++r)
                vc[ct][r] = tb[(4 * g + r) * TSTR + ct * 16 + cc];

        float part[4];
#pragma unroll
        for (int ct = 0; ct < 4; ++ct) {
            float m = fmaxf(fmaxf(lg[ct][0], lg[ct][1]), fmaxf(lg[ct][2], lg[ct][3]));
            m = fmaxf(m, __shfl_xor(m, 16));
            m = fmaxf(m, __shfl_xor(m, 32));
            float e0 = __expf(lg[ct][0] - m), e1 = __expf(lg[ct][1] - m);
            float e2 = __expf(lg[ct][2] - m), e3 = __expf(lg[ct][3] - m);
            float s = e0 + e1 + e2 + e3;
            s += __shfl_xor(s, 16);
            s += __shfl_xor(s, 32);
            float inv = 1.0f / s;
            float pt = 0.f;
            pt = fmaf(e0 * inv, vc[ct][0] + pe[ct][0], pt);
            pt = fmaf(e1 * inv, vc[ct][1] + pe[ct][1], pt);
            pt = fmaf(e2 * inv, vc[ct][2] + pe[ct][2], pt);
            pt = fmaf(e3 * inv, vc[ct][3] + pe[ct][3], pt);
            pt += __shfl_xor(pt, 16);
            pt += __shfl_xor(pt, 32);
            part[ct] = pt;
        }
        float resv = part[0];
        resv = is1 ? part[1] : resv;
        resv = is2 ? part[2] : resv;
        resv = is3 ? part[3] : resv;
        resv += feats[(size_t)p * 64 + lane];
        out[(size_t)p * 64 + lane] = resv;
        lsum += resv;
        lsq = fmaf(resv, resv, lsq);
    }
    atomicAdd(&bns[lane], lsum);
    atomicAdd(&bnq[lane], lsq);
    __syncthreads();
    if (tid < 64) {
        atomicAdd(&gsum[tid], bns[tid]);
        atomicAdd(&gsq[tid], bnq[tid]);
    }
}

// ---------------- stats zero + BatchNorm finalize ----------------
__global__ void zero_stats_kernel(float* s) {
    if (threadIdx.x < 128) s[threadIdx.x] = 0.f;
}

__global__ __launch_bounds__(256) void bn_final_kernel(float* __restrict__ out,
                                                       const float* __restrict__ gsum,
                                                       const float* __restrict__ gsq,
                                                       const float* __restrict__ bnw,
                                                       const float* __restrict__ bnb) {
    __shared__ float sc[64], sh[64];
    int tid = threadIdx.x;
    if (tid < 64) {
        const float invN = 1.0f / (float)(BB * NN);
        float mean = gsum[tid] * invN;
        float var = gsq[tid] * invN - mean * mean;
        float inv = rsqrtf(var + 1e-5f);
        float scale = inv * bnw[tid];
        sc[tid] = scale;
        sh[tid] = bnb[tid] - mean * scale;
    }
    __syncthreads();
    size_t total = (size_t)BB * NN * 64;
    for (size_t i = (size_t)blockIdx.x * 256 + tid; i < total; i += (size_t)gridDim.x * 256) {
        int c = (int)(i & 63);
        out[i] = fmaf(out[i], sc[c], sh[c]);
    }
}

extern "C" void kernel_launch(void* const* d_in, const int* in_sizes, int n_in,
                              void* d_out, int out_size, void* d_ws, size_t ws_size,
                              hipStream_t stream) {
    const float* xyz = (const float*)d_in[0];
    const float* feats = (const float*)d_in[1];
    const float* Wq = (const float*)d_in[2];
    const float* Wk = (const float*)d_in[3];
    const float* Wv = (const float*)d_in[4];
    const float* d1w = (const float*)d_in[5];
    const float* d1b = (const float*)d_in[6];
    const float* d2w = (const float*)d_in[7];
    const float* d2b = (const float*)d_in[8];
    const float* g1w = (const float*)d_in[9];
    const float* g1b = (const float*)d_in[10];
    const float* g2w = (const float*)d_in[11];
    const float* g2b = (const float*)d_in[12];
    const float* bnw = (const float*)d_in[13];
    const float* bnb = (const float*)d_in[14];
    float* out = (float*)d_out;

    char* ws = (char*)d_ws;
    size_t off = 0;
    int* knnIdx = (int*)(ws + off); off += (size_t)BB * NN * 16 * 4;
    float* Q = (float*)(ws + off); off += (size_t)BB * NN * 64 * 4;
    float* Kf = (float*)(ws + off); off += (size_t)BB * NN * 64 * 4;
    float* Vf = (float*)(ws + off); off += (size_t)BB * NN * 64 * 4;
    float* stats = (float*)(ws + off);  // 128 floats

    hipLaunchKernelGGL(zero_stats_kernel, dim3(1), dim3(128), 0, stream, stats);
    hipLaunchKernelGGL(qkv_kernel, dim3(512), dim3(256), 0, stream,
                       feats, Wq, Wk, Wv, Q, Kf, Vf);
    hipLaunchKernelGGL(knn_kernel, dim3(BB * 256), dim3(256), 0, stream, xyz, knnIdx);
    hipLaunchKernelGGL(attn_kernel, dim3(512), dim3(256), 0, stream,
                       xyz, feats, Q, Kf, Vf, knnIdx,
                       d1w, d1b, d2w, d2b, g1w, g1b, g2w, g2b,
                       out, stats, stats + 64);
    hipLaunchKernelGGL(bn_final_kernel, dim3(512), dim3(256), 0, stream,
                       out, stats, stats + 64, bnw, bnb);
}

// Round 6
// 280.090 us; speedup vs baseline: 3.2748x; 1.2507x over previous
//
#include <hip/hip_runtime.h>
#include <hip/hip_bf16.h>

#define BB 8
#define NN 4096
#define DD 64

typedef __attribute__((ext_vector_type(8))) short short8;
typedef __attribute__((ext_vector_type(4))) float f32x4;

__device__ __forceinline__ short f2bf(float f) {
    __hip_bfloat16 h = __float2bfloat16(f);
    return __builtin_bit_cast(short, h);
}

__device__ __forceinline__ float bcastf(float x, int l) {
    return __int_as_float(__builtin_amdgcn_readlane(__float_as_int(x), l));
}

// ---------------- exact kNN: wave = 1 query (round-4 proven logic, verbatim) ----------------
__device__ __forceinline__ void bsort64(float& d, int& i, int lane) {
#pragma unroll
    for (int s = 2; s <= 64; s <<= 1) {
#pragma unroll
        for (int m = s >> 1; m >= 1; m >>= 1) {
            float dp = __shfl_xor(d, m);
            int ip = __shfl_xor(i, m);
            bool up = ((lane & s) == 0);
            bool lower = ((lane & m) == 0);
            bool less = (d < dp) || (d == dp && i < ip);
            bool takeMine = (less == (up == lower));
            d = takeMine ? d : dp;
            i = takeMine ? i : ip;
        }
    }
}

__device__ __forceinline__ float pdist(const float* X, int c, float qx, float qy,
                                       float qz, float sqq) {
    float cx = X[c * 3], cy = X[c * 3 + 1], cz = X[c * 3 + 2];
    float sqc = __fadd_rn(__fadd_rn(__fmul_rn(cx, cx), __fmul_rn(cy, cy)), __fmul_rn(cz, cz));
    float dot = __fadd_rn(__fadd_rn(__fmul_rn(qx, cx), __fmul_rn(qy, cy)), __fmul_rn(qz, cz));
    return __fadd_rn(__fadd_rn(sqq, sqc), -__fmul_rn(2.0f, dot));
}

// block = 512 threads = 8 waves sharing one X stage; 32 queries per block (4 per wave)
// grid = BB * 128. Per-query inner loop byte-identical to the passing round-4 kernel.
__global__ __launch_bounds__(512) void knn_kernel(const float* __restrict__ xyz,
                                                  int* __restrict__ knnIdx) {
    __shared__ __align__(16) float X[NN * 3];
    __shared__ float bufD[8][64];
    __shared__ int bufI[8][64];
    int tid = threadIdx.x;
    int b = blockIdx.x >> 7;        // 128 blocks per batch
    int qgroup = blockIdx.x & 127;  // 32 queries per block
    const float* xb = xyz + (size_t)b * NN * 3;
    for (int i = tid; i < NN * 3 / 4; i += 512)
        ((float4*)X)[i] = ((const float4*)xb)[i];
    __syncthreads();

    int wid = tid >> 6, lane = tid & 63;
    float* bD = bufD[wid];
    int* bI = bufI[wid];

    for (int qi = 0; qi < 4; ++qi) {
        int qq = qgroup * 32 + wid * 4 + qi;
        float qx = X[qq * 3], qy = X[qq * 3 + 1], qz = X[qq * 3 + 2];
        float sqq = __fadd_rn(__fadd_rn(__fmul_rn(qx, qx), __fmul_rn(qy, qy)),
                              __fmul_rn(qz, qz));
        // round 0: candidates 0..63
        float d0 = pdist(X, lane, qx, qy, qz, sqq);
        int i0 = lane;
        bsort64(d0, i0, lane);
        if (lane < 16) { bD[lane] = d0; bI[lane] = i0; }
        int count = 16;
        float t = __shfl(d0, 15);

        for (int r = 1; r < 64; ++r) {
            int cidx = r * 64 + lane;
            float dc = pdist(X, cidx, qx, qy, qz, sqq);
            unsigned long long mask = __ballot(dc < t);
            while (mask) {
                int avail = 64 - count;
                unsigned long long below = mask & ((1ull << lane) - 1ull);
                int pos = __popcll(below);
                bool mine = (mask >> lane) & 1;
                if (mine && pos < avail) {
                    bD[count + pos] = dc;
                    bI[count + pos] = cidx;
                }
                int nq = __popcll(mask);
                if (nq <= avail) {
                    count += nq;
                    mask = 0;
                } else {
                    count = 64;
                    mask = __ballot(mine && pos >= avail);
                    // sort-cut to exact top-16 of all seen so far
                    float sd = (lane < count) ? bD[lane] : 3.0e38f;
                    int si = (lane < count) ? bI[lane] : 0x7fffffff;
                    bsort64(sd, si, lane);
                    if (lane < 16) { bD[lane] = sd; bI[lane] = si; }
                    count = 16;
                    t = __shfl(sd, 15);
                    mask &= __ballot(dc < t);
                }
            }
        }
        float fd = (lane < count) ? bD[lane] : 3.0e38f;
        int fi = (lane < count) ? bI[lane] : 0x7fffffff;
        bsort64(fd, fi, lane);
        if (lane < 16) knnIdx[((size_t)b * NN + qq) * 16 + lane] = fi;
    }
}

// ---------------- q/k/v projections (f32, readlane broadcast) ----------------
__global__ __launch_bounds__(256) void qkv_kernel(const float* __restrict__ feats,
                                                  const float* __restrict__ Wq,
                                                  const float* __restrict__ Wk,
                                                  const float* __restrict__ Wv,
                                                  float* __restrict__ Q,
                                                  float* __restrict__ Kf,
                                                  float* __restrict__ Vf) {
    __shared__ float Aq[4096], Ak[4096], Av[4096];
    int tid = threadIdx.x;
    for (int i = tid; i < 4096; i += 256) { Aq[i] = Wq[i]; Ak[i] = Wk[i]; Av[i] = Wv[i]; }
    __syncthreads();
    int lane = tid & 63, wid = tid >> 6;
    int gw = blockIdx.x * 4 + wid, nw = gridDim.x * 4;
    for (int r = gw; r < BB * NN; r += nw) {
        float f = feats[(size_t)r * 64 + lane];
        float aq = 0.f, ak = 0.f, av = 0.f;
#pragma unroll 8
        for (int h = 0; h < 64; ++h) {
            float s = bcastf(f, h);
            aq = fmaf(s, Aq[h * 64 + lane], aq);
            ak = fmaf(s, Ak[h * 64 + lane], ak);
            av = fmaf(s, Av[h * 64 + lane], av);
        }
        Q[(size_t)r * 64 + lane] = aq;
        Kf[(size_t)r * 64 + lane] = ak;
        Vf[(size_t)r * 64 + lane] = av;
    }
}

// ---------------- fused MFMA attention: wave = 1 point ----------------
#define TSTR 68

__global__ __launch_bounds__(256, 2) void attn_kernel(
    const float* __restrict__ xyz, const float* __restrict__ feats,
    const float* __restrict__ Q, const float* __restrict__ Kf, const float* __restrict__ Vf,
    const int* __restrict__ knnIdx,
    const float* __restrict__ d1w, const float* __restrict__ d1b,
    const float* __restrict__ d2w, const float* __restrict__ d2b,
    const float* __restrict__ g1w, const float* __restrict__ g1b,
    const float* __restrict__ g2w, const float* __restrict__ g2b,
    float* __restrict__ out, float* __restrict__ gsum, float* __restrict__ gsq) {
    __shared__ float d1s[4][64];
    __shared__ __align__(16) float tbuf[4][16 * TSTR];
    __shared__ float bns[64], bnq[64];
    int tid = threadIdx.x;
    if (tid < 256) {
        int a = tid >> 6, ch = tid & 63;
        d1s[a][ch] = (a < 3) ? d1w[a * 64 + ch] : d1b[ch];
    }
    if (tid < 64) { bns[tid] = 0.f; bnq[tid] = 0.f; }
    __syncthreads();

    int lane = tid & 63, wid = tid >> 6;
    int cc = lane & 15, g = lane >> 4;
    float* tb = tbuf[wid];

    short8 bd2[2][4], bg1[2][4], bg2[2][4];
#pragma unroll
    for (int kt = 0; kt < 2; ++kt)
#pragma unroll
        for (int ct = 0; ct < 4; ++ct) {
            short8 f2, fg1, fg2;
#pragma unroll
            for (int j = 0; j < 8; ++j) {
                int kk = kt * 32 + g * 8 + j, col = ct * 16 + cc;
                f2[j] = f2bf(d2w[kk * 64 + col]);
                fg1[j] = f2bf(g1w[kk * 64 + col]);
                fg2[j] = f2bf(g2w[kk * 64 + col]);
            }
            bd2[kt][ct] = f2; bg1[kt][ct] = fg1; bg2[kt][ct] = fg2;
        }
    float b2c[4], gb1c[4], gb2c[4];
#pragma unroll
    for (int ct = 0; ct < 4; ++ct) {
        b2c[ct] = d2b[ct * 16 + cc];
        gb1c[ct] = g1b[ct * 16 + cc];
        gb2c[ct] = g2b[ct * 16 + cc];
    }
    bool is1 = (g == 1), is2 = (g == 2), is3 = (g == 3);

    int gw = blockIdx.x * 4 + wid, nw = gridDim.x * 4;
    float lsum = 0.f, lsq = 0.f;

    for (int p = gw; p < BB * NN; p += nw) {
        int b = p >> 12;
        int idxA = knnIdx[(size_t)p * 16 + cc];
        int nb = (b << 12) + idxA;

        const float* Qp = Q + (size_t)p * 64;
        const float* Kp = Kf + (size_t)nb * 64;
        f32x4 q0 = *(const f32x4*)&Qp[g * 8], q1 = *(const f32x4*)&Qp[g * 8 + 4];
        f32x4 q2 = *(const f32x4*)&Qp[32 + g * 8], q3 = *(const f32x4*)&Qp[32 + g * 8 + 4];
        f32x4 k0 = *(const f32x4*)&Kp[g * 8], k1 = *(const f32x4*)&Kp[g * 8 + 4];
        f32x4 k2 = *(const f32x4*)&Kp[32 + g * 8], k3 = *(const f32x4*)&Kp[32 + g * 8 + 4];

        float sx = xyz[(size_t)p * 3], sy = xyz[(size_t)p * 3 + 1], sz = xyz[(size_t)p * 3 + 2];
        float dx = sx - xyz[(size_t)nb * 3];
        float dy = sy - xyz[(size_t)nb * 3 + 1];
        float dz = sz - xyz[(size_t)nb * 3 + 2];

        short8 ha[2];
#pragma unroll
        for (int kt = 0; kt < 2; ++kt) {
            short8 hv;
#pragma unroll
            for (int hb = 0; hb < 2; ++hb) {
                int ch = kt * 32 + g * 8 + hb * 4;
                f32x4 w0 = *(const f32x4*)&d1s[0][ch];
                f32x4 w1 = *(const f32x4*)&d1s[1][ch];
                f32x4 w2 = *(const f32x4*)&d1s[2][ch];
                f32x4 bb_ = *(const f32x4*)&d1s[3][ch];
#pragma unroll
                for (int j = 0; j < 4; ++j) {
                    float h = bb_[j] + dx * w0[j] + dy * w1[j] + dz * w2[j];
                    hv[hb * 4 + j] = f2bf(fmaxf(h, 0.f));
                }
            }
            ha[kt] = hv;
        }

        f32x4 pe[4];
#pragma unroll
        for (int ct = 0; ct < 4; ++ct) {
            f32x4 acc = {0.f, 0.f, 0.f, 0.f};
            acc = __builtin_amdgcn_mfma_f32_16x16x32_bf16(ha[0], bd2[0][ct], acc, 0, 0, 0);
            acc = __builtin_amdgcn_mfma_f32_16x16x32_bf16(ha[1], bd2[1][ct], acc, 0, 0, 0);
#pragma unroll
            for (int r = 0; r < 4; ++r) pe[ct][r] = acc[r] + b2c[ct];
        }

#pragma unroll
        for (int ct = 0; ct < 4; ++ct)
#pragma unroll
            for (int r = 0; r < 4; ++r)
                tb[(4 * g + r) * TSTR + ct * 16 + cc] = pe[ct][r];
        short8 xa[2];
        {
            f32x4 p0 = *(const f32x4*)&tb[cc * TSTR + g * 8];
            f32x4 p1 = *(const f32x4*)&tb[cc * TSTR + g * 8 + 4];
            f32x4 p2 = *(const f32x4*)&tb[cc * TSTR + 32 + g * 8];
            f32x4 p3 = *(const f32x4*)&tb[cc * TSTR + 32 + g * 8 + 4];
            f32x4 x0 = q0 - k0 + p0, x1 = q1 - k1 + p1;
            f32x4 x2 = q2 - k2 + p2, x3 = q3 - k3 + p3;
            short8 v0, v1;
#pragma unroll
            for (int j = 0; j < 4; ++j) {
                v0[j] = f2bf(x0[j]); v0[4 + j] = f2bf(x1[j]);
                v1[j] = f2bf(x2[j]); v1[4 + j] = f2bf(x3[j]);
            }
            xa[0] = v0; xa[1] = v1;
        }

        f32x4 h2[4];
#pragma unroll
        for (int ct = 0; ct < 4; ++ct) {
            f32x4 acc = {0.f, 0.f, 0.f, 0.f};
            acc = __builtin_amdgcn_mfma_f32_16x16x32_bf16(xa[0], bg1[0][ct], acc, 0, 0, 0);
            acc = __builtin_amdgcn_mfma_f32_16x16x32_bf16(xa[1], bg1[1][ct], acc, 0, 0, 0);
#pragma unroll
            for (int r = 0; r < 4; ++r) h2[ct][r] = fmaxf(acc[r] + gb1c[ct], 0.f);
        }

#pragma unroll
        for (int ct = 0; ct < 4; ++ct)
#pragma unroll
            for (int r = 0; r < 4; ++r)
                tb[(4 * g + r) * TSTR + ct * 16 + cc] = h2[ct][r];
        short8 h2a[2];
        {
            f32x4 p0 = *(const f32x4*)&tb[cc * TSTR + g * 8];
            f32x4 p1 = *(const f32x4*)&tb[cc * TSTR + g * 8 + 4];
            f32x4 p2 = *(const f32x4*)&tb[cc * TSTR + 32 + g * 8];
            f32x4 p3 = *(const f32x4*)&tb[cc * TSTR + 32 + g * 8 + 4];
            short8 v0, v1;
#pragma unroll
            for (int j = 0; j < 4; ++j) {
                v0[j] = f2bf(p0[j]); v0[4 + j] = f2bf(p1[j]);
                v1[j] = f2bf(p2[j]); v1[4 + j] = f2bf(p3[j]);
            }
            h2a[0] = v0; h2a[1] = v1;
        }

        f32x4 lg[4];
#pragma unroll
        for (int ct = 0; ct < 4; ++ct) {
            f32x4 acc = {0.f, 0.f, 0.f, 0.f};
            acc = __builtin_amdgcn_mfma_f32_16x16x32_bf16(h2a[0], bg2[0][ct], acc, 0, 0, 0);
            acc = __builtin_amdgcn_mfma_f32_16x16x32_bf16(h2a[1], bg2[1][ct], acc, 0, 0, 0);
#pragma unroll
            for (int r = 0; r < 4; ++r) lg[ct][r] = acc[r] + gb2c[ct];
        }

        const float* Vp = Vf + (size_t)nb * 64;
        {
            f32x4 v0 = *(const f32x4*)&Vp[g * 8], v1 = *(const f32x4*)&Vp[g * 8 + 4];
            f32x4 v2 = *(const f32x4*)&Vp[32 + g * 8], v3 = *(const f32x4*)&Vp[32 + g * 8 + 4];
            *(f32x4*)&tb[cc * TSTR + g * 8] = v0;
            *(f32x4*)&tb[cc * TSTR + g * 8 + 4] = v1;
            *(f32x4*)&tb[cc * TSTR + 32 + g * 8] = v2;
            *(f32x4*)&tb[cc * TSTR + 32 + g * 8 + 4] = v3;
        }
        f32x4 vc[4];
#pragma unroll
        for (int ct = 0; ct < 4; ++ct)
#pragma unroll
            for (int r = 0; r < 4; ++r)
                vc[ct][r] = tb[(4 * g + r) * TSTR + ct * 16 + cc];

        float part[4];
#pragma unroll
        for (int ct = 0; ct < 4; ++ct) {
            float m = fmaxf(fmaxf(lg[ct][0], lg[ct][1]), fmaxf(lg[ct][2], lg[ct][3]));
            m = fmaxf(m, __shfl_xor(m, 16));
            m = fmaxf(m, __shfl_xor(m, 32));
            float e0 = __expf(lg[ct][0] - m), e1 = __expf(lg[ct][1] - m);
            float e2 = __expf(lg[ct][2] - m), e3 = __expf(lg[ct][3] - m);
            float s = e0 + e1 + e2 + e3;
            s += __shfl_xor(s, 16);
            s += __shfl_xor(s, 32);
            float inv = 1.0f / s;
            float pt = 0.f;
            pt = fmaf(e0 * inv, vc[ct][0] + pe[ct][0], pt);
            pt = fmaf(e1 * inv, vc[ct][1] + pe[ct][1], pt);
            pt = fmaf(e2 * inv, vc[ct][2] + pe[ct][2], pt);
            pt = fmaf(e3 * inv, vc[ct][3] + pe[ct][3], pt);
            pt += __shfl_xor(pt, 16);
            pt += __shfl_xor(pt, 32);
            part[ct] = pt;
        }
        float resv = part[0];
        resv = is1 ? part[1] : resv;
        resv = is2 ? part[2] : resv;
        resv = is3 ? part[3] : resv;
        resv += feats[(size_t)p * 64 + lane];
        out[(size_t)p * 64 + lane] = resv;
        lsum += resv;
        lsq = fmaf(resv, resv, lsq);
    }
    atomicAdd(&bns[lane], lsum);
    atomicAdd(&bnq[lane], lsq);
    __syncthreads();
    if (tid < 64) {
        atomicAdd(&gsum[tid], bns[tid]);
        atomicAdd(&gsq[tid], bnq[tid]);
    }
}

// ---------------- stats zero + BatchNorm finalize ----------------
__global__ void zero_stats_kernel(float* s) {
    if (threadIdx.x < 128) s[threadIdx.x] = 0.f;
}

__global__ __launch_bounds__(256) void bn_final_kernel(float* __restrict__ out,
                                                       const float* __restrict__ gsum,
                                                       const float* __restrict__ gsq,
                                                       const float* __restrict__ bnw,
                                                       const float* __restrict__ bnb) {
    __shared__ float sc[64], sh[64];
    int tid = threadIdx.x;
    if (tid < 64) {
        const float invN = 1.0f / (float)(BB * NN);
        float mean = gsum[tid] * invN;
        float var = gsq[tid] * invN - mean * mean;
        float inv = rsqrtf(var + 1e-5f);
        float scale = inv * bnw[tid];
        sc[tid] = scale;
        sh[tid] = bnb[tid] - mean * scale;
    }
    __syncthreads();
    size_t total = (size_t)BB * NN * 64;
    for (size_t i = (size_t)blockIdx.x * 256 + tid; i < total; i += (size_t)gridDim.x * 256) {
        int c = (int)(i & 63);
        out[i] = fmaf(out[i], sc[c], sh[c]);
    }
}

extern "C" void kernel_launch(void* const* d_in, const int* in_sizes, int n_in,
                              void* d_out, int out_size, void* d_ws, size_t ws_size,
                              hipStream_t stream) {
    const float* xyz = (const float*)d_in[0];
    const float* feats = (const float*)d_in[1];
    const float* Wq = (const float*)d_in[2];
    const float* Wk = (const float*)d_in[3];
    const float* Wv = (const float*)d_in[4];
    const float* d1w = (const float*)d_in[5];
    const float* d1b = (const float*)d_in[6];
    const float* d2w = (const float*)d_in[7];
    const float* d2b = (const float*)d_in[8];
    const float* g1w = (const float*)d_in[9];
    const float* g1b = (const float*)d_in[10];
    const float* g2w = (const float*)d_in[11];
    const float* g2b = (const float*)d_in[12];
    const float* bnw = (const float*)d_in[13];
    const float* bnb = (const float*)d_in[14];
    float* out = (float*)d_out;

    char* ws = (char*)d_ws;
    size_t off = 0;
    int* knnIdx = (int*)(ws + off); off += (size_t)BB * NN * 16 * 4;
    float* Q = (float*)(ws + off); off += (size_t)BB * NN * 64 * 4;
    float* Kf = (float*)(ws + off); off += (size_t)BB * NN * 64 * 4;
    float* Vf = (float*)(ws + off); off += (size_t)BB * NN * 64 * 4;
    float* stats = (float*)(ws + off);  // 128 floats

    hipLaunchKernelGGL(zero_stats_kernel, dim3(1), dim3(128), 0, stream, stats);
    hipLaunchKernelGGL(qkv_kernel, dim3(512), dim3(256), 0, stream,
                       feats, Wq, Wk, Wv, Q, Kf, Vf);
    hipLaunchKernelGGL(knn_kernel, dim3(BB * 128), dim3(512), 0, stream, xyz, knnIdx);
    hipLaunchKernelGGL(attn_kernel, dim3(512), dim3(256), 0, stream,
                       xyz, feats, Q, Kf, Vf, knnIdx,
                       d1w, d1b, d2w, d2b, g1w, g1b, g2w, g2b,
                       out, stats, stats + 64);
    hipLaunchKernelGGL(bn_final_kernel, dim3(512), dim3(256), 0, stream,
                       out, stats, stats + 64, bnw, bnb);
}

// Round 7
// 272.506 us; speedup vs baseline: 3.3659x; 1.0278x over previous
//
#include <hip/hip_runtime.h>
#include <hip/hip_bf16.h>

#define BB 8
#define NN 4096
#define DD 64

typedef __attribute__((ext_vector_type(8))) short short8;
typedef __attribute__((ext_vector_type(4))) float f32x4;

__device__ __forceinline__ short f2bf(float f) {
    __hip_bfloat16 h = __float2bfloat16(f);
    return __builtin_bit_cast(short, h);
}

__device__ __forceinline__ float bcastf(float x, int l) {
    return __int_as_float(__builtin_amdgcn_readlane(__float_as_int(x), l));
}

// ---------------- exact kNN: wave = 1 query (round-4 proven state machine) ----------------
__device__ __forceinline__ void bsort64(float& d, int& i, int lane) {
#pragma unroll
    for (int s = 2; s <= 64; s <<= 1) {
#pragma unroll
        for (int m = s >> 1; m >= 1; m >>= 1) {
            float dp = __shfl_xor(d, m);
            int ip = __shfl_xor(i, m);
            bool up = ((lane & s) == 0);
            bool lower = ((lane & m) == 0);
            bool less = (d < dp) || (d == dp && i < ip);
            bool takeMine = (less == (up == lower));
            d = takeMine ? d : dp;
            i = takeMine ? i : ip;
        }
    }
}

__device__ __forceinline__ float sq3(float x, float y, float z) {
    return __fadd_rn(__fadd_rn(__fmul_rn(x, x), __fmul_rn(y, y)), __fmul_rn(z, z));
}

// dist from precomputed-sq float4 entry; rounding chain identical to prior pdist
__device__ __forceinline__ float pdistv(float qx, float qy, float qz, float sqq, float4 c4) {
    float dot = __fadd_rn(__fadd_rn(__fmul_rn(qx, c4.x), __fmul_rn(qy, c4.y)),
                          __fmul_rn(qz, c4.z));
    return __fadd_rn(__fadd_rn(sqq, c4.w), -__fmul_rn(2.0f, dot));
}

// block = 512 threads = 8 waves sharing one X4 stage; 32 queries per block (4 per wave)
__global__ __launch_bounds__(512) void knn_kernel(const float* __restrict__ xyz,
                                                  int* __restrict__ knnIdx) {
    __shared__ __align__(16) float4 X4[NN];     // (x,y,z,|c|^2), 64KB
    __shared__ float bufD[8][64];
    __shared__ int bufI[8][64];
    int tid = threadIdx.x;
    int b = blockIdx.x >> 7;        // 128 blocks per batch
    int qgroup = blockIdx.x & 127;  // 32 queries per block
    const float* xb = xyz + (size_t)b * NN * 3;
    for (int i = tid; i < NN; i += 512) {
        float x = xb[i * 3], y = xb[i * 3 + 1], z = xb[i * 3 + 2];
        X4[i] = make_float4(x, y, z, sq3(x, y, z));
    }
    __syncthreads();

    int wid = tid >> 6, lane = tid & 63;
    float* bD = bufD[wid];
    int* bI = bufI[wid];

    for (int qi = 0; qi < 4; ++qi) {
        int qq = qgroup * 32 + wid * 4 + qi;
        float4 qv = X4[qq];
        float qx = qv.x, qy = qv.y, qz = qv.z, sqq = qv.w;
        // round 0: candidates 0..63
        float d0 = pdistv(qx, qy, qz, sqq, X4[lane]);
        int i0 = lane;
        bsort64(d0, i0, lane);
        if (lane < 16) { bD[lane] = d0; bI[lane] = i0; }
        int count = 16;
        float t = __shfl(d0, 15);

        for (int r = 1; r < 64; ++r) {
            int cidx = r * 64 + lane;
            float dc = pdistv(qx, qy, qz, sqq, X4[cidx]);
            unsigned long long mask = __ballot(dc < t);
            while (mask) {
                int avail = 64 - count;
                unsigned long long below = mask & ((1ull << lane) - 1ull);
                int pos = __popcll(below);
                bool mine = (mask >> lane) & 1;
                if (mine && pos < avail) {
                    bD[count + pos] = dc;
                    bI[count + pos] = cidx;
                }
                int nq = __popcll(mask);
                if (nq <= avail) {
                    count += nq;
                    mask = 0;
                } else {
                    count = 64;
                    mask = __ballot(mine && pos >= avail);
                    // sort-cut to exact top-16 of all seen so far
                    float sd = (lane < count) ? bD[lane] : 3.0e38f;
                    int si = (lane < count) ? bI[lane] : 0x7fffffff;
                    bsort64(sd, si, lane);
                    if (lane < 16) { bD[lane] = sd; bI[lane] = si; }
                    count = 16;
                    t = __shfl(sd, 15);
                    mask &= __ballot(dc < t);
                }
            }
        }
        float fd = (lane < count) ? bD[lane] : 3.0e38f;
        int fi = (lane < count) ? bI[lane] : 0x7fffffff;
        bsort64(fd, fi, lane);
        if (lane < 16) knnIdx[((size_t)b * NN + qq) * 16 + lane] = fi;
    }
}

// ---------------- q/k/v projections (f32, readlane broadcast) ----------------
__global__ __launch_bounds__(256) void qkv_kernel(const float* __restrict__ feats,
                                                  const float* __restrict__ Wq,
                                                  const float* __restrict__ Wk,
                                                  const float* __restrict__ Wv,
                                                  float* __restrict__ Q,
                                                  float* __restrict__ Kf,
                                                  float* __restrict__ Vf) {
    __shared__ float Aq[4096], Ak[4096], Av[4096];
    int tid = threadIdx.x;
    for (int i = tid; i < 4096; i += 256) { Aq[i] = Wq[i]; Ak[i] = Wk[i]; Av[i] = Wv[i]; }
    __syncthreads();
    int lane = tid & 63, wid = tid >> 6;
    int gw = blockIdx.x * 4 + wid, nw = gridDim.x * 4;
    for (int r = gw; r < BB * NN; r += nw) {
        float f = feats[(size_t)r * 64 + lane];
        float aq = 0.f, ak = 0.f, av = 0.f;
#pragma unroll 8
        for (int h = 0; h < 64; ++h) {
            float s = bcastf(f, h);
            aq = fmaf(s, Aq[h * 64 + lane], aq);
            ak = fmaf(s, Ak[h * 64 + lane], ak);
            av = fmaf(s, Av[h * 64 + lane], av);
        }
        Q[(size_t)r * 64 + lane] = aq;
        Kf[(size_t)r * 64 + lane] = ak;
        Vf[(size_t)r * 64 + lane] = av;
    }
}

// ---------------- fused MFMA attention: wave = 1 point ----------------
#define TSTR 68

__global__ __launch_bounds__(256, 2) void attn_kernel(
    const float* __restrict__ xyz, const float* __restrict__ feats,
    const float* __restrict__ Q, const float* __restrict__ Kf, const float* __restrict__ Vf,
    const int* __restrict__ knnIdx,
    const float* __restrict__ d1w, const float* __restrict__ d1b,
    const float* __restrict__ d2w, const float* __restrict__ d2b,
    const float* __restrict__ g1w, const float* __restrict__ g1b,
    const float* __restrict__ g2w, const float* __restrict__ g2b,
    float* __restrict__ out, float* __restrict__ gsum, float* __restrict__ gsq) {
    __shared__ float d1s[4][64];
    __shared__ __align__(16) float tbuf[4][16 * TSTR];
    __shared__ float bns[64], bnq[64];
    int tid = threadIdx.x;
    if (tid < 256) {
        int a = tid >> 6, ch = tid & 63;
        d1s[a][ch] = (a < 3) ? d1w[a * 64 + ch] : d1b[ch];
    }
    if (tid < 64) { bns[tid] = 0.f; bnq[tid] = 0.f; }
    __syncthreads();

    int lane = tid & 63, wid = tid >> 6;
    int cc = lane & 15, g = lane >> 4;
    float* tb = tbuf[wid];

    short8 bd2[2][4], bg1[2][4], bg2[2][4];
#pragma unroll
    for (int kt = 0; kt < 2; ++kt)
#pragma unroll
        for (int ct = 0; ct < 4; ++ct) {
            short8 f2, fg1, fg2;
#pragma unroll
            for (int j = 0; j < 8; ++j) {
                int kk = kt * 32 + g * 8 + j, col = ct * 16 + cc;
                f2[j] = f2bf(d2w[kk * 64 + col]);
                fg1[j] = f2bf(g1w[kk * 64 + col]);
                fg2[j] = f2bf(g2w[kk * 64 + col]);
            }
            bd2[kt][ct] = f2; bg1[kt][ct] = fg1; bg2[kt][ct] = fg2;
        }
    float b2c[4], gb1c[4], gb2c[4];
#pragma unroll
    for (int ct = 0; ct < 4; ++ct) {
        b2c[ct] = d2b[ct * 16 + cc];
        gb1c[ct] = g1b[ct * 16 + cc];
        gb2c[ct] = g2b[ct * 16 + cc];
    }
    bool is1 = (g == 1), is2 = (g == 2), is3 = (g == 3);

    int gw = blockIdx.x * 4 + wid, nw = gridDim.x * 4;
    float lsum = 0.f, lsq = 0.f;

    for (int p = gw; p < BB * NN; p += nw) {
        int b = p >> 12;
        int idxA = knnIdx[(size_t)p * 16 + cc];
        int nb = (b << 12) + idxA;

        const float* Qp = Q + (size_t)p * 64;
        const float* Kp = Kf + (size_t)nb * 64;
        f32x4 q0 = *(const f32x4*)&Qp[g * 8], q1 = *(const f32x4*)&Qp[g * 8 + 4];
        f32x4 q2 = *(const f32x4*)&Qp[32 + g * 8], q3 = *(const f32x4*)&Qp[32 + g * 8 + 4];
        f32x4 k0 = *(const f32x4*)&Kp[g * 8], k1 = *(const f32x4*)&Kp[g * 8 + 4];
        f32x4 k2 = *(const f32x4*)&Kp[32 + g * 8], k3 = *(const f32x4*)&Kp[32 + g * 8 + 4];

        float sx = xyz[(size_t)p * 3], sy = xyz[(size_t)p * 3 + 1], sz = xyz[(size_t)p * 3 + 2];
        float dx = sx - xyz[(size_t)nb * 3];
        float dy = sy - xyz[(size_t)nb * 3 + 1];
        float dz = sz - xyz[(size_t)nb * 3 + 2];

        short8 ha[2];
#pragma unroll
        for (int kt = 0; kt < 2; ++kt) {
            short8 hv;
#pragma unroll
            for (int hb = 0; hb < 2; ++hb) {
                int ch = kt * 32 + g * 8 + hb * 4;
                f32x4 w0 = *(const f32x4*)&d1s[0][ch];
                f32x4 w1 = *(const f32x4*)&d1s[1][ch];
                f32x4 w2 = *(const f32x4*)&d1s[2][ch];
                f32x4 bb_ = *(const f32x4*)&d1s[3][ch];
#pragma unroll
                for (int j = 0; j < 4; ++j) {
                    float h = bb_[j] + dx * w0[j] + dy * w1[j] + dz * w2[j];
                    hv[hb * 4 + j] = f2bf(fmaxf(h, 0.f));
                }
            }
            ha[kt] = hv;
        }

        f32x4 pe[4];
#pragma unroll
        for (int ct = 0; ct < 4; ++ct) {
            f32x4 acc = {0.f, 0.f, 0.f, 0.f};
            acc = __builtin_amdgcn_mfma_f32_16x16x32_bf16(ha[0], bd2[0][ct], acc, 0, 0, 0);
            acc = __builtin_amdgcn_mfma_f32_16x16x32_bf16(ha[1], bd2[1][ct], acc, 0, 0, 0);
#pragma unroll
            for (int r = 0; r < 4; ++r) pe[ct][r] = acc[r] + b2c[ct];
        }

#pragma unroll
        for (int ct = 0; ct < 4; ++ct)
#pragma unroll
            for (int r = 0; r < 4; ++r)
                tb[(4 * g + r) * TSTR + ct * 16 + cc] = pe[ct][r];
        short8 xa[2];
        {
            f32x4 p0 = *(const f32x4*)&tb[cc * TSTR + g * 8];
            f32x4 p1 = *(const f32x4*)&tb[cc * TSTR + g * 8 + 4];
            f32x4 p2 = *(const f32x4*)&tb[cc * TSTR + 32 + g * 8];
            f32x4 p3 = *(const f32x4*)&tb[cc * TSTR + 32 + g * 8 + 4];
            f32x4 x0 = q0 - k0 + p0, x1 = q1 - k1 + p1;
            f32x4 x2 = q2 - k2 + p2, x3 = q3 - k3 + p3;
            short8 v0, v1;
#pragma unroll
            for (int j = 0; j < 4; ++j) {
                v0[j] = f2bf(x0[j]); v0[4 + j] = f2bf(x1[j]);
                v1[j] = f2bf(x2[j]); v1[4 + j] = f2bf(x3[j]);
            }
            xa[0] = v0; xa[1] = v1;
        }

        f32x4 h2[4];
#pragma unroll
        for (int ct = 0; ct < 4; ++ct) {
            f32x4 acc = {0.f, 0.f, 0.f, 0.f};
            acc = __builtin_amdgcn_mfma_f32_16x16x32_bf16(xa[0], bg1[0][ct], acc, 0, 0, 0);
            acc = __builtin_amdgcn_mfma_f32_16x16x32_bf16(xa[1], bg1[1][ct], acc, 0, 0, 0);
#pragma unroll
            for (int r = 0; r < 4; ++r) h2[ct][r] = fmaxf(acc[r] + gb1c[ct], 0.f);
        }

#pragma unroll
        for (int ct = 0; ct < 4; ++ct)
#pragma unroll
            for (int r = 0; r < 4; ++r)
                tb[(4 * g + r) * TSTR + ct * 16 + cc] = h2[ct][r];
        short8 h2a[2];
        {
            f32x4 p0 = *(const f32x4*)&tb[cc * TSTR + g * 8];
            f32x4 p1 = *(const f32x4*)&tb[cc * TSTR + g * 8 + 4];
            f32x4 p2 = *(const f32x4*)&tb[cc * TSTR + 32 + g * 8];
            f32x4 p3 = *(const f32x4*)&tb[cc * TSTR + 32 + g * 8 + 4];
            short8 v0, v1;
#pragma unroll
            for (int j = 0; j < 4; ++j) {
                v0[j] = f2bf(p0[j]); v0[4 + j] = f2bf(p1[j]);
                v1[j] = f2bf(p2[j]); v1[4 + j] = f2bf(p3[j]);
            }
            h2a[0] = v0; h2a[1] = v1;
        }

        f32x4 lg[4];
#pragma unroll
        for (int ct = 0; ct < 4; ++ct) {
            f32x4 acc = {0.f, 0.f, 0.f, 0.f};
            acc = __builtin_amdgcn_mfma_f32_16x16x32_bf16(h2a[0], bg2[0][ct], acc, 0, 0, 0);
            acc = __builtin_amdgcn_mfma_f32_16x16x32_bf16(h2a[1], bg2[1][ct], acc, 0, 0, 0);
#pragma unroll
            for (int r = 0; r < 4; ++r) lg[ct][r] = acc[r] + gb2c[ct];
        }

        const float* Vp = Vf + (size_t)nb * 64;
        {
            f32x4 v0 = *(const f32x4*)&Vp[g * 8], v1 = *(const f32x4*)&Vp[g * 8 + 4];
            f32x4 v2 = *(const f32x4*)&Vp[32 + g * 8], v3 = *(const f32x4*)&Vp[32 + g * 8 + 4];
            *(f32x4*)&tb[cc * TSTR + g * 8] = v0;
            *(f32x4*)&tb[cc * TSTR + g * 8 + 4] = v1;
            *(f32x4*)&tb[cc * TSTR + 32 + g * 8] = v2;
            *(f32x4*)&tb[cc * TSTR + 32 + g * 8 + 4] = v3;
        }
        f32x4 vc[4];
#pragma unroll
        for (int ct = 0; ct < 4; ++ct)
#pragma unroll
            for (int r = 0; r < 4; ++r)
                vc[ct][r] = tb[(4 * g + r) * TSTR + ct * 16 + cc];

        float part[4];
#pragma unroll
        for (int ct = 0; ct < 4; ++ct) {
            float m = fmaxf(fmaxf(lg[ct][0], lg[ct][1]), fmaxf(lg[ct][2], lg[ct][3]));
            m = fmaxf(m, __shfl_xor(m, 16));
            m = fmaxf(m, __shfl_xor(m, 32));
            float e0 = __expf(lg[ct][0] - m), e1 = __expf(lg[ct][1] - m);
            float e2 = __expf(lg[ct][2] - m), e3 = __expf(lg[ct][3] - m);
            float s = e0 + e1 + e2 + e3;
            s += __shfl_xor(s, 16);
            s += __shfl_xor(s, 32);
            float inv = 1.0f / s;
            float pt = 0.f;
            pt = fmaf(e0 * inv, vc[ct][0] + pe[ct][0], pt);
            pt = fmaf(e1 * inv, vc[ct][1] + pe[ct][1], pt);
            pt = fmaf(e2 * inv, vc[ct][2] + pe[ct][2], pt);
            pt = fmaf(e3 * inv, vc[ct][3] + pe[ct][3], pt);
            pt += __shfl_xor(pt, 16);
            pt += __shfl_xor(pt, 32);
            part[ct] = pt;
        }
        float resv = part[0];
        resv = is1 ? part[1] : resv;
        resv = is2 ? part[2] : resv;
        resv = is3 ? part[3] : resv;
        resv += feats[(size_t)p * 64 + lane];
        out[(size_t)p * 64 + lane] = resv;
        lsum += resv;
        lsq = fmaf(resv, resv, lsq);
    }
    atomicAdd(&bns[lane], lsum);
    atomicAdd(&bnq[lane], lsq);
    __syncthreads();
    if (tid < 64) {
        atomicAdd(&gsum[tid], bns[tid]);
        atomicAdd(&gsq[tid], bnq[tid]);
    }
}

// ---------------- stats zero + BatchNorm finalize ----------------
__global__ void zero_stats_kernel(float* s) {
    if (threadIdx.x < 128) s[threadIdx.x] = 0.f;
}

__global__ __launch_bounds__(256) void bn_final_kernel(float* __restrict__ out,
                                                       const float* __restrict__ gsum,
                                                       const float* __restrict__ gsq,
                                                       const float* __restrict__ bnw,
                                                       const float* __restrict__ bnb) {
    __shared__ float sc[64], sh[64];
    int tid = threadIdx.x;
    if (tid < 64) {
        const float invN = 1.0f / (float)(BB * NN);
        float mean = gsum[tid] * invN;
        float var = gsq[tid] * invN - mean * mean;
        float inv = rsqrtf(var + 1e-5f);
        float scale = inv * bnw[tid];
        sc[tid] = scale;
        sh[tid] = bnb[tid] - mean * scale;
    }
    __syncthreads();
    size_t total = (size_t)BB * NN * 64;
    for (size_t i = (size_t)blockIdx.x * 256 + tid; i < total; i += (size_t)gridDim.x * 256) {
        int c = (int)(i & 63);
        out[i] = fmaf(out[i], sc[c], sh[c]);
    }
}

extern "C" void kernel_launch(void* const* d_in, const int* in_sizes, int n_in,
                              void* d_out, int out_size, void* d_ws, size_t ws_size,
                              hipStream_t stream) {
    const float* xyz = (const float*)d_in[0];
    const float* feats = (const float*)d_in[1];
    const float* Wq = (const float*)d_in[2];
    const float* Wk = (const float*)d_in[3];
    const float* Wv = (const float*)d_in[4];
    const float* d1w = (const float*)d_in[5];
    const float* d1b = (const float*)d_in[6];
    const float* d2w = (const float*)d_in[7];
    const float* d2b = (const float*)d_in[8];
    const float* g1w = (const float*)d_in[9];
    const float* g1b = (const float*)d_in[10];
    const float* g2w = (const float*)d_in[11];
    const float* g2b = (const float*)d_in[12];
    const float* bnw = (const float*)d_in[13];
    const float* bnb = (const float*)d_in[14];
    float* out = (float*)d_out;

    char* ws = (char*)d_ws;
    size_t off = 0;
    int* knnIdx = (int*)(ws + off); off += (size_t)BB * NN * 16 * 4;
    float* Q = (float*)(ws + off); off += (size_t)BB * NN * 64 * 4;
    float* Kf = (float*)(ws + off); off += (size_t)BB * NN * 64 * 4;
    float* Vf = (float*)(ws + off); off += (size_t)BB * NN * 64 * 4;
    float* stats = (float*)(ws + off);  // 128 floats

    hipLaunchKernelGGL(zero_stats_kernel, dim3(1), dim3(128), 0, stream, stats);
    hipLaunchKernelGGL(qkv_kernel, dim3(512), dim3(256), 0, stream,
                       feats, Wq, Wk, Wv, Q, Kf, Vf);
    hipLaunchKernelGGL(knn_kernel, dim3(BB * 128), dim3(512), 0, stream, xyz, knnIdx);
    hipLaunchKernelGGL(attn_kernel, dim3(512), dim3(256), 0, stream,
                       xyz, feats, Q, Kf, Vf, knnIdx,
                       d1w, d1b, d2w, d2b, g1w, g1b, g2w, g2b,
                       out, stats, stats + 64);
    hipLaunchKernelGGL(bn_final_kernel, dim3(512), dim3(256), 0, stream,
                       out, stats, stats + 64, bnw, bnb);
}